// Round 1
// baseline (65.993 us; speedup 1.0000x reference)
//
#include <hip/hip_runtime.h>
#include <hip/hip_bf16.h>

#define N_ROWS 8192
#define DIM 128

typedef short v8s __attribute__((ext_vector_type(8)));   // 8 bf16 (4 VGPRs) MFMA A/B frag
typedef float v4f __attribute__((ext_vector_type(4)));   // MFMA C/D frag

constexpr int NS = 8;                 // column splits (blockIdx.y)
constexpr int CW = N_ROWS / NS;       // 1024 columns per split
constexpr float THRESH = 0.25f;       // sqrt(sqrt(d^2)) + 1e-8 < 0.5  <=>  |d| < 0.25
constexpr float C1 = 14.426950408889634f;  // 10*log2(e): exp(10*dot-10) = 2^(C1*dot - C1)

__device__ __forceinline__ unsigned short f2bf(float f) {
  __hip_bfloat16 h = __float2bfloat16(f);
  return __builtin_bit_cast(unsigned short, h);
}

// ---------------- kernel 1: L2-normalize rows, cast to bf16 ----------------
__global__ __launch_bounds__(256) void knorm(const float* __restrict__ emb,
                                             unsigned short* __restrict__ ebf) {
  const int row  = blockIdx.x * 4 + (threadIdx.x >> 6);  // one wave per row
  const int lane = threadIdx.x & 63;
  const float2 v = *reinterpret_cast<const float2*>(emb + (size_t)row * DIM + lane * 2);
  float ss = fmaf(v.x, v.x, v.y * v.y);
#pragma unroll
  for (int off = 32; off > 0; off >>= 1) ss += __shfl_xor(ss, off);
  const float rn = 1.0f / sqrtf(ss);
  const unsigned int packed =
      (unsigned int)f2bf(v.x * rn) | ((unsigned int)f2bf(v.y * rn) << 16);
  *reinterpret_cast<unsigned int*>(ebf + (size_t)row * DIM + lane * 2) = packed;
}

// ---------------- kernel 2: fused sim-GEMM + row stats ----------------
// block = 256 threads = 4 waves (2x2 wave grid). Block tile: 128 rows x 128 cols
// per j-step; each block covers a 1024-column split. A frags persistent in regs;
// B frags loaded direct from global (e_bf16 is 2MB -> L2 resident). No LDS.
__global__ __launch_bounds__(256) void kmain(const unsigned short* __restrict__ ebf,
                                             const float* __restrict__ props,
                                             float* __restrict__ part) {
  const int lane = threadIdx.x & 63;
  const int w    = threadIdx.x >> 6;
  const int wm   = w >> 1;             // row half of block (0..1)
  const int wn   = w & 1;              // col half of block (0..1)
  const int l15  = lane & 15;
  const int g    = lane >> 4;          // 0..3
  const int i0   = blockIdx.x * 128;
  const int jbase = blockIdx.y * CW;

  const int rowA = i0 + wm * 64 + l15;   // + m*16
  const int kb   = g * 8;                // k element offset within a 32-k step

  // A fragments: lane l holds A[row = l&15][k = (l>>4)*8 + 0..7] (16B contiguous)
  v8s aF[4][4];
#pragma unroll
  for (int m = 0; m < 4; ++m)
#pragma unroll
    for (int k = 0; k < 4; ++k)
      aF[m][k] = *reinterpret_cast<const v8s*>(
          ebf + (size_t)(rowA + m * 16) * DIM + k * 32 + kb);

  // per-slot row properties; slot s=m*4+r -> row = i0+wm*64+m*16+g*4+r (C/D layout m89)
  float pr[16];
#pragma unroll
  for (int m = 0; m < 4; ++m)
#pragma unroll
    for (int r = 0; r < 4; ++r)
      pr[m * 4 + r] = props[i0 + wm * 64 + m * 16 + g * 4 + r];

  float es[16], ms[16], ct[16];
#pragma unroll
  for (int s = 0; s < 16; ++s) { es[s] = 0.f; ms[s] = 0.f; ct[s] = 0.f; }

  const int rbase = i0 + wm * 64 + g * 4;  // col - rbase == m*16+r  <=> col == row
  const v4f vzero = {0.f, 0.f, 0.f, 0.f};

  for (int jt = 0; jt < CW / 128; ++jt) {
    const int j0 = jbase + jt * 128;
#pragma unroll
    for (int n = 0; n < 4; ++n) {
      const int col = j0 + wn * 64 + n * 16 + l15;  // B frag col AND C frag col
      v8s bF[4];
#pragma unroll
      for (int k = 0; k < 4; ++k)
        bF[k] = *reinterpret_cast<const v8s*>(
            ebf + (size_t)col * DIM + k * 32 + kb);

      v4f acc[4];
#pragma unroll
      for (int m = 0; m < 4; ++m) acc[m] = vzero;
#pragma unroll
      for (int k = 0; k < 4; ++k)
#pragma unroll
        for (int m = 0; m < 4; ++m)
          acc[m] = __builtin_amdgcn_mfma_f32_16x16x32_bf16(aF[m][k], bF[k], acc[m], 0, 0, 0);

      const float pc  = props[col];
      const int   cmb = col - rbase;
#pragma unroll
      for (int m = 0; m < 4; ++m)
#pragma unroll
        for (int r = 0; r < 4; ++r) {
          const int   s   = m * 4 + r;
          const float dot = acc[m][r];
          const bool  neq = (cmb != (m * 16 + r));      // exclude diagonal
          const float ex  = exp2f(fmaf(dot, C1, -C1));  // exp(10*dot - 10)
          es[s] += neq ? ex : 0.f;
          const bool msk = neq && (fabsf(pr[s] - pc) < THRESH);
          ms[s] += msk ? dot : 0.f;
          ct[s] += msk ? 1.f : 0.f;
        }
    }
  }

  // reduce across the 16 lanes (columns) of each g-group
#pragma unroll
  for (int s = 0; s < 16; ++s) {
#pragma unroll
    for (int off = 1; off < 16; off <<= 1) {
      es[s] += __shfl_xor(es[s], off);
      ms[s] += __shfl_xor(ms[s], off);
      ct[s] += __shfl_xor(ct[s], off);
    }
  }

  // lane q (=l15) writes slot q. Static-index select (rule #20: no runtime array idx).
  float oes = 0.f, oms = 0.f, oct = 0.f;
#pragma unroll
  for (int q = 0; q < 16; ++q)
    if (l15 == q) { oes = es[q]; oms = ms[q]; oct = ct[q]; }

  const int sp  = blockIdx.y * 2 + wn;           // 16 partial slots, race-free
  float* p0     = part + (size_t)sp * 3 * N_ROWS;
  const int row = i0 + wm * 64 + (l15 >> 2) * 16 + g * 4 + (l15 & 3);
  p0[row]              = oes;
  p0[N_ROWS + row]     = oms;
  p0[2 * N_ROWS + row] = oct;
}

// ---------------- kernel 3: per-row finalize + per-block partial sums ----------------
__global__ __launch_bounds__(256) void kreduce(const float* __restrict__ part,
                                               float* __restrict__ bs,
                                               float* __restrict__ bc) {
  const int row = blockIdx.x * 256 + threadIdx.x;
  float es = 0.f, ms = 0.f, ct = 0.f;
#pragma unroll
  for (int sp = 0; sp < 16; ++sp) {
    const float* p0 = part + (size_t)sp * 3 * N_ROWS;
    es += p0[row];
    ms += p0[N_ROWS + row];
    ct += p0[2 * N_ROWS + row];
  }
  const float lse = 10.0f + logf(es);                       // logsumexp, M=10
  const float per = (ct * lse - 10.0f * ms) / fmaxf(ct, 1.0f);
  float val = (ct > 0.f) ? per : 0.f;
  float vld = (ct > 0.f) ? 1.f : 0.f;
#pragma unroll
  for (int off = 32; off > 0; off >>= 1) {
    val += __shfl_xor(val, off);
    vld += __shfl_xor(vld, off);
  }
  __shared__ float sv[4], sc[4];
  const int wid = threadIdx.x >> 6;
  if ((threadIdx.x & 63) == 0) { sv[wid] = val; sc[wid] = vld; }
  __syncthreads();
  if (threadIdx.x == 0) {
    bs[blockIdx.x] = sv[0] + sv[1] + sv[2] + sv[3];
    bc[blockIdx.x] = sc[0] + sc[1] + sc[2] + sc[3];
  }
}

// ---------------- kernel 4: final scalar ----------------
__global__ __launch_bounds__(64) void kfin(const float* __restrict__ bs,
                                           const float* __restrict__ bc,
                                           float* __restrict__ out) {
  const int l = threadIdx.x;
  float s = (l < 32) ? bs[l] : 0.f;
  float c = (l < 32) ? bc[l] : 0.f;
#pragma unroll
  for (int off = 32; off > 0; off >>= 1) {
    s += __shfl_xor(s, off);
    c += __shfl_xor(c, off);
  }
  if (l == 0) out[0] = (c > 0.f) ? (s / c) : 0.f;
}

extern "C" void kernel_launch(void* const* d_in, const int* in_sizes, int n_in,
                              void* d_out, int out_size, void* d_ws, size_t ws_size,
                              hipStream_t stream) {
  const float* emb   = (const float*)d_in[0];
  const float* props = (const float*)d_in[1];
  float* out = (float*)d_out;

  // ws layout: [0, 2MB) bf16 normalized embeddings; then 16*3*N f32 partials; then 64 f32
  unsigned short* ebf = (unsigned short*)d_ws;
  const size_t EBF_BYTES  = (size_t)N_ROWS * DIM * 2;
  const size_t PART_BYTES = (size_t)16 * 3 * N_ROWS * 4;
  float* part = (float*)((char*)d_ws + EBF_BYTES);
  float* bs   = (float*)((char*)d_ws + EBF_BYTES + PART_BYTES);
  float* bc   = bs + 32;

  knorm<<<N_ROWS / 4, 256, 0, stream>>>(emb, ebf);
  kmain<<<dim3(N_ROWS / 128, NS), 256, 0, stream>>>(ebf, props, part);
  kreduce<<<N_ROWS / 256, 256, 0, stream>>>(part, bs, bc);
  kfin<<<1, 64, 0, stream>>>(bs, bc, out);
}